// Round 3
// baseline (1146.016 us; speedup 1.0000x reference)
//
#include <hip/hip_runtime.h>
#include <stdint.h>

typedef unsigned int u32;
typedef unsigned long long u64;

#define KSEL 6000      // pre_nms_limit
#define PC   1000      // proposal_count
#define NW   94        // ceil(KSEL/64) removal-mask words
#define CAP  8000      // candidate collection cap
#define HB   65536     // 16-bit histogram bins

__device__ inline u64 shfl64(u64 v, int src) {
    int lo = __shfl((int)(u32)(v & 0xFFFFFFFFULL), src);
    int hi = __shfl((int)(u32)(v >> 32), src);
    return ((u64)(u32)hi << 32) | (u32)lo;
}

// ---------------- K0: order-preserving keys + top-16-bit histogram ----------------
__global__ void k_keys_hist(const float* __restrict__ probs, u32* __restrict__ keys,
                            u32* __restrict__ hist16, int A)
{
    int a = blockIdx.x * 256 + threadIdx.x;
    int b = blockIdx.y;
    if (a >= A) return;
    size_t i = (size_t)b * A + a;
    u32 u = __float_as_uint(probs[i * 2 + 1]);
    u = (u & 0x80000000u) ? ~u : (u | 0x80000000u);   // float order -> uint order
    keys[i] = u;
    atomicAdd(&hist16[(size_t)b * HB + (u >> 16)], 1u);
}

// ---------------- K1: pick threshold bin from a 65536-bin histogram ----------------
// LEVEL 0: hist16 -> prefix16[b], rem[b].  LEVEL 1: hist2 -> exact 32-bit T[b].
template <int LEVEL>
__global__ __launch_bounds__(1024)
void k_pick(const u32* __restrict__ hist, const u32* __restrict__ rem_in,
            const u32* __restrict__ pfx_in, u32* __restrict__ pfx_out,
            u32* __restrict__ rem_out, u32* __restrict__ T_out)
{
    __shared__ u32 part[1024];
    const int t = threadIdx.x, b = blockIdx.x;
    const u32* h = hist + (size_t)b * HB;
    const int hi = HB - 1 - t * 64;            // my 64-bin chunk, descending
    u32 s = 0;
#pragma unroll 8
    for (int q = 0; q < 64; ++q) s += h[hi - q];
    part[t] = s;
    __syncthreads();
    u32 run = s;                               // run == part[t] invariant
    for (int off = 1; off < 1024; off <<= 1) {
        u32 add = (t >= off) ? part[t - off] : 0u;
        __syncthreads();
        run += add;
        part[t] = run;
        __syncthreads();
    }
    const u32 rem = (LEVEL == 0) ? (u32)KSEL : rem_in[b];
    u32 excl = run - s;                        // count in all chunks above mine
    if (excl < rem && rem <= run) {            // threshold bin is in my chunk
        u32 cum = excl;
        for (int q = 0; q < 64; ++q) {
            u32 c = h[hi - q];
            if (cum + c >= rem) {
                u32 bin = (u32)(hi - q);
                if (LEVEL == 0) { pfx_out[b] = bin; rem_out[b] = rem - cum; }
                else            { T_out[b] = (pfx_in[b] << 16) | bin; }
                break;
            }
            cum += c;
        }
    }
}

// ---------------- K2: second-level histogram (low 16 bits within chosen prefix) ----------------
__global__ void k_hist2(const u32* __restrict__ keys, const u32* __restrict__ pfx,
                        u32* __restrict__ hist2, int A)
{
    int a = blockIdx.x * 256 + threadIdx.x;
    int b = blockIdx.y;
    if (a >= A) return;
    u32 k = keys[(size_t)b * A + a];
    if ((k >> 16) == pfx[b])
        atomicAdd(&hist2[(size_t)b * HB + (k & 0xFFFFu)], 1u);
}

// ---------------- K3: collect (~key, index) for all keys >= T ----------------
__global__ void k_collect(const u32* __restrict__ keys, const u32* __restrict__ T,
                          u32* __restrict__ cnt, u64* __restrict__ cand, int A)
{
    int a = blockIdx.x * 256 + threadIdx.x;
    int b = blockIdx.y;
    if (a >= A) return;
    u32 k = keys[(size_t)b * A + a];
    if (k >= T[b]) {
        u32 pos = atomicAdd(&cnt[b], 1u);
        if (pos < CAP) cand[(size_t)b * CAP + pos] = ((u64)(~k) << 32) | (u32)a;
    }
}

// ---------------- K4: per-sample stable sort (score desc, idx asc) + box decode ----------------
__global__ __launch_bounds__(1024)
void k_sortdecode(const float* __restrict__ probs, const float* __restrict__ deltas,
                  const float* __restrict__ anchors, const u64* __restrict__ cand,
                  const u32* __restrict__ cntg, float* __restrict__ boxes_sel,
                  float* __restrict__ scores_sel, int A)
{
    __shared__ u64 sbuf[8192];                 // 64 KiB
    const int tid = threadIdx.x, b = blockIdx.x;
    int cnt = (int)cntg[b]; if (cnt > CAP) cnt = CAP;
    for (int i = tid; i < cnt; i += 1024) sbuf[i] = cand[(size_t)b * CAP + i];
    for (int i = cnt + tid; i < 8192; i += 1024) sbuf[i] = ~0ULL;
    __syncthreads();

    for (int kk = 2; kk <= 8192; kk <<= 1)
        for (int jj = kk >> 1; jj > 0; jj >>= 1) {
            for (int i = tid; i < 8192; i += 1024) {
                int ixj = i ^ jj;
                if (ixj > i) {
                    u64 x = sbuf[i], y = sbuf[ixj];
                    bool up = ((i & kk) == 0);
                    if ((x > y) == up) { sbuf[i] = y; sbuf[ixj] = x; }
                }
            }
            __syncthreads();
        }

    for (int s = tid; s < KSEL; s += 1024) {
        u64 ck = sbuf[s];
        int a = (int)(u32)ck;
        float score = probs[((size_t)b * A + a) * 2 + 1];
        float4 an = ((const float4*)anchors)[a];
        float4 dl = ((const float4*)deltas)[(size_t)b * A + a];
        float h = an.z - an.x, w = an.w - an.y;
        float cy = an.x + 0.5f * h + dl.x * 0.1f * h;
        float cx = an.y + 0.5f * w + dl.y * 0.1f * w;
        h *= expf(dl.z * 0.2f);
        w *= expf(dl.w * 0.2f);
        float y1 = cy - 0.5f * h, x1 = cx - 0.5f * w;
        float y2 = y1 + h,        x2 = x1 + w;
        y1 = fminf(fmaxf(y1, 0.f), 1024.f);
        x1 = fminf(fmaxf(x1, 0.f), 1024.f);
        y2 = fminf(fmaxf(y2, 0.f), 1024.f);
        x2 = fminf(fmaxf(x2, 0.f), 1024.f);
        ((float4*)boxes_sel)[(size_t)b * KSEL + s] = make_float4(y1, x1, y2, x2);
        scores_sel[(size_t)b * KSEL + s] = score;
    }
}

// ---------------- K5: 64-bit suppression mask matrix ----------------
__global__ __launch_bounds__(64)
void k_iou(const float* __restrict__ boxes_sel, u64* __restrict__ mask)
{
    __shared__ float4 rowb[64];
    int t = threadIdx.x;
    int bi = blockIdx.x, bj = blockIdx.y, b = blockIdx.z;
    const float4* boxes = (const float4*)boxes_sel + (size_t)b * KSEL;
    int ri = bi * 64 + t;
    int j  = bj * 64 + t;
    rowb[t] = (ri < KSEL) ? boxes[ri] : make_float4(0.f, 0.f, 0.f, 0.f);
    float4 cb = (j < KSEL) ? boxes[j] : make_float4(0.f, 0.f, 0.f, 0.f);
    float areaC = (cb.z - cb.x) * (cb.w - cb.y);
    __syncthreads();
    u64 myword = 0;
    for (int r = 0; r < 64; ++r) {
        float4 rb = rowb[r];
        float areaR = (rb.z - rb.x) * (rb.w - rb.y);
        float iy1 = fmaxf(rb.x, cb.x), ix1 = fmaxf(rb.y, cb.y);
        float iy2 = fminf(rb.z, cb.z), ix2 = fminf(rb.w, cb.w);
        float inter = fmaxf(iy2 - iy1, 0.f) * fmaxf(ix2 - ix1, 0.f);
        float uni = fmaxf(areaR + areaC - inter, 1e-10f);
        bool sup = (j < KSEL) && (inter > 0.7f * uni);
        u64 word = __ballot(sup ? 1 : 0);
        if (r == t) myword = word;
    }
    if (ri < KSEL) mask[((size_t)b * KSEL + ri) * NW + bj] = myword;
}

// ---------------- K6: chunked greedy NMS, 1 wave/sample ----------------
// lane l holds removal words l (remv0) and 64+l (remv1). Per 64-box chunk:
// resolve intra-chunk suppression in registers via the diagonal mask word,
// then batch-OR kept boxes' full rows (independent loads -> one L2 latency/chunk).
__global__ __launch_bounds__(64)
void k_nms(const u64* __restrict__ mask, int* __restrict__ keepidx, int* __restrict__ nkept)
{
    const int lane = threadIdx.x;
    const int b = blockIdx.x;
    const u64* mb = mask + (size_t)b * KSEL * NW;
    int* ki = keepidx + b * PC;

    u64 remv0 = 0, remv1 = 0;
    int kept = 0;

    int ri0 = lane;                                        // chunk 0 diag row
    u64 mcur = (ri0 < KSEL) ? mb[(size_t)ri0 * NW + 0] : 0ULL;

    for (int c = 0; c < NW; ++c) {
        int rin = (c + 1) * 64 + lane;                     // prefetch next diag word
        u64 mnext = (c + 1 < NW && rin < KSEL) ? mb[(size_t)rin * NW + (c + 1)] : 0ULL;

        u64 r = (c < 64) ? shfl64(remv0, c) : shfl64(remv1, c - 64);
        int rb = KSEL - c * 64;
        u64 valid = (rb >= 64) ? ~0ULL : ((1ULL << rb) - 1ULL);
        u64 pend = valid & ~r;
        u64 keep = 0;
        while (pend) {                                     // wave-uniform greedy resolve
            int bb = __ffsll((unsigned long long)pend) - 1;
            keep |= 1ULL << bb;
            u64 sup = shfl64(mcur, bb);
            pend &= ~(sup | (1ULL << bb));
        }
        // emit kept indices (ascending = rank order)
        u64 kk = keep;
        while (kk) {
            int bb = __ffsll((unsigned long long)kk) - 1; kk &= kk - 1;
            if (kept < PC && lane == 0) ki[kept] = c * 64 + bb;
            ++kept;
        }
        if (kept >= PC) { kept = PC; break; }
        // OR kept rows into distributed removal mask (for future chunks)
        kk = keep;
        while (kk) {
            int bb = __ffsll((unsigned long long)kk) - 1; kk &= kk - 1;
            const u64* row = mb + (size_t)(c * 64 + bb) * NW;
            remv0 |= row[lane];
            if (lane < NW - 64) remv1 |= row[64 + lane];
        }
        mcur = mnext;
    }
    if (lane == 0) nkept[b] = kept;
}

// ---------------- K7: gather kept -> output ----------------
__global__ void k_out(const float* __restrict__ boxes_sel, const float* __restrict__ scores_sel,
                      const int* __restrict__ keepidx, const int* __restrict__ nkept,
                      float* __restrict__ out, int B)
{
    int idx = blockIdx.x * 256 + threadIdx.x;
    int nb = B * PC * 4;
    int ns = B * PC;
    if (idx < nb) {
        int b = idx / (PC * 4);
        int r = idx % (PC * 4);
        int s = r >> 2, c = r & 3;
        float v = 0.f;
        if (s < nkept[b]) {
            int i = keepidx[b * PC + s];
            v = boxes_sel[((size_t)b * KSEL + i) * 4 + c] * (1.0f / 1024.0f);
        }
        out[idx] = v;
    } else if (idx < nb + ns) {
        int r = idx - nb;
        int b = r / PC, s = r % PC;
        float v = 0.f;
        if (s < nkept[b]) v = scores_sel[(size_t)b * KSEL + keepidx[b * PC + s]];
        out[idx] = v;
    } else if (idx < nb + ns + B) {
        int b = idx - nb - ns;
        out[idx] = (float)nkept[b];
    }
}

extern "C" void kernel_launch(void* const* d_in, const int* in_sizes, int n_in,
                              void* d_out, int out_size, void* d_ws, size_t ws_size,
                              hipStream_t stream)
{
    const float* probs   = (const float*)d_in[0];
    const float* deltas  = (const float*)d_in[1];
    const float* anchors = (const float*)d_in[2];
    int A = in_sizes[2] / 4;
    int B = in_sizes[0] / (2 * A);

    char* w = (char*)d_ws;
    size_t off = 0;
    // zero region (single memset): hist16 | hist2 | cnt
    u32* hist16 = (u32*)(w + off);     off += (size_t)B * HB * sizeof(u32);
    u32* hist2  = (u32*)(w + off);     off += (size_t)B * HB * sizeof(u32);
    u32* cnt    = (u32*)(w + off);     off += (size_t)B * sizeof(u32);
    size_t zero_bytes = off;
    off = (off + 15) & ~(size_t)15;
    u32* keys = (u32*)(w + off);       off += (size_t)B * A * sizeof(u32);
    u32* pfx  = (u32*)(w + off);       off += (size_t)B * sizeof(u32);
    u32* remq = (u32*)(w + off);       off += (size_t)B * sizeof(u32);
    u32* T    = (u32*)(w + off);       off += (size_t)B * sizeof(u32);
    off = (off + 15) & ~(size_t)15;
    u64* cand = (u64*)(w + off);       off += (size_t)B * CAP * sizeof(u64);
    float* boxes_sel  = (float*)(w + off); off += (size_t)B * KSEL * 4 * sizeof(float);
    float* scores_sel = (float*)(w + off); off += (size_t)B * KSEL * sizeof(float);
    int* keepidx = (int*)(w + off);        off += (size_t)B * PC * sizeof(int);
    int* nkept   = (int*)(w + off);        off += (size_t)B * sizeof(int);
    off = (off + 15) & ~(size_t)15;
    u64* mask = (u64*)(w + off);           off += (size_t)B * KSEL * NW * sizeof(u64);
    // total ~25.3 MB

    hipMemsetAsync(hist16, 0, zero_bytes, stream);

    dim3 gA((A + 255) / 256, B);
    k_keys_hist<<<gA, 256, 0, stream>>>(probs, keys, hist16, A);
    k_pick<0><<<B, 1024, 0, stream>>>(hist16, nullptr, nullptr, pfx, remq, nullptr);
    k_hist2<<<gA, 256, 0, stream>>>(keys, pfx, hist2, A);
    k_pick<1><<<B, 1024, 0, stream>>>(hist2, remq, pfx, nullptr, nullptr, T);
    k_collect<<<gA, 256, 0, stream>>>(keys, T, cnt, cand, A);
    k_sortdecode<<<B, 1024, 0, stream>>>(probs, deltas, anchors, cand, cnt,
                                         boxes_sel, scores_sel, A);
    k_iou<<<dim3(NW, NW, B), 64, 0, stream>>>(boxes_sel, mask);
    k_nms<<<B, 64, 0, stream>>>(mask, keepidx, nkept);
    int outn = B * (PC * 4 + PC + 1);
    k_out<<<(outn + 255) / 256, 256, 0, stream>>>(boxes_sel, scores_sel, keepidx, nkept,
                                                  (float*)d_out, B);
}

// Round 4
// 820.376 us; speedup vs baseline: 1.3969x; 1.3969x over previous
//
#include <hip/hip_runtime.h>
#include <stdint.h>

typedef unsigned int u32;
typedef unsigned long long u64;

#define KSEL 6000      // pre_nms_limit
#define PC   1000      // proposal_count
#define NW   94        // ceil(KSEL/64) removal-mask words
#define CAP  8000      // candidate collection cap
#define HB   65536     // 16-bit histogram bins

// broadcast lane `src` (wave-uniform) of a per-lane u64 to all lanes, result in SGPRs
__device__ inline u64 bcast64(u64 v, int src) {
    int s = __builtin_amdgcn_readfirstlane(src);
    u32 lo = __builtin_amdgcn_readlane((u32)(v & 0xFFFFFFFFULL), s);
    u32 hi = __builtin_amdgcn_readlane((u32)(v >> 32), s);
    return ((u64)hi << 32) | lo;
}

// ---------------- K0: order-preserving keys + top-16-bit histogram ----------------
__global__ void k_keys_hist(const float* __restrict__ probs, u32* __restrict__ keys,
                            u32* __restrict__ hist16, int A)
{
    int a = blockIdx.x * 256 + threadIdx.x;
    int b = blockIdx.y;
    if (a >= A) return;
    size_t i = (size_t)b * A + a;
    u32 u = __float_as_uint(probs[i * 2 + 1]);
    u = (u & 0x80000000u) ? ~u : (u | 0x80000000u);   // float order -> uint order
    keys[i] = u;
    atomicAdd(&hist16[(size_t)b * HB + (u >> 16)], 1u);
}

// ---------------- K1: pick threshold bin from a 65536-bin histogram ----------------
template <int LEVEL>
__global__ __launch_bounds__(1024)
void k_pick(const u32* __restrict__ hist, const u32* __restrict__ rem_in,
            const u32* __restrict__ pfx_in, u32* __restrict__ pfx_out,
            u32* __restrict__ rem_out, u32* __restrict__ T_out)
{
    __shared__ u32 part[1024];
    const int t = threadIdx.x, b = blockIdx.x;
    const u32* h = hist + (size_t)b * HB;
    const int hi = HB - 1 - t * 64;            // my 64-bin chunk, descending
    u32 s = 0;
#pragma unroll 8
    for (int q = 0; q < 64; ++q) s += h[hi - q];
    part[t] = s;
    __syncthreads();
    u32 run = s;
    for (int off = 1; off < 1024; off <<= 1) {
        u32 add = (t >= off) ? part[t - off] : 0u;
        __syncthreads();
        run += add;
        part[t] = run;
        __syncthreads();
    }
    const u32 rem = (LEVEL == 0) ? (u32)KSEL : rem_in[b];
    u32 excl = run - s;
    if (excl < rem && rem <= run) {            // threshold bin is in my chunk
        u32 cum = excl;
        for (int q = 0; q < 64; ++q) {
            u32 c = h[hi - q];
            if (cum + c >= rem) {
                u32 bin = (u32)(hi - q);
                if (LEVEL == 0) { pfx_out[b] = bin; rem_out[b] = rem - cum; }
                else            { T_out[b] = (pfx_in[b] << 16) | bin; }
                break;
            }
            cum += c;
        }
    }
}

// ---------------- K2: second-level histogram ----------------
__global__ void k_hist2(const u32* __restrict__ keys, const u32* __restrict__ pfx,
                        u32* __restrict__ hist2, int A)
{
    int a = blockIdx.x * 256 + threadIdx.x;
    int b = blockIdx.y;
    if (a >= A) return;
    u32 k = keys[(size_t)b * A + a];
    if ((k >> 16) == pfx[b])
        atomicAdd(&hist2[(size_t)b * HB + (k & 0xFFFFu)], 1u);
}

// ---------------- K3: collect (~key, index) for all keys >= T ----------------
__global__ void k_collect(const u32* __restrict__ keys, const u32* __restrict__ T,
                          u32* __restrict__ cnt, u64* __restrict__ cand, int A)
{
    int a = blockIdx.x * 256 + threadIdx.x;
    int b = blockIdx.y;
    if (a >= A) return;
    u32 k = keys[(size_t)b * A + a];
    if (k >= T[b]) {
        u32 pos = atomicAdd(&cnt[b], 1u);
        if (pos < CAP) cand[(size_t)b * CAP + pos] = ((u64)(~k) << 32) | (u32)a;
    }
}

// ---------------- K4: per-sample stable sort + box decode ----------------
__global__ __launch_bounds__(1024)
void k_sortdecode(const float* __restrict__ probs, const float* __restrict__ deltas,
                  const float* __restrict__ anchors, const u64* __restrict__ cand,
                  const u32* __restrict__ cntg, float* __restrict__ boxes_sel,
                  float* __restrict__ scores_sel, int A)
{
    __shared__ u64 sbuf[8192];                 // 64 KiB
    const int tid = threadIdx.x, b = blockIdx.x;
    int cnt = (int)cntg[b]; if (cnt > CAP) cnt = CAP;
    for (int i = tid; i < cnt; i += 1024) sbuf[i] = cand[(size_t)b * CAP + i];
    for (int i = cnt + tid; i < 8192; i += 1024) sbuf[i] = ~0ULL;
    __syncthreads();

    for (int kk = 2; kk <= 8192; kk <<= 1)
        for (int jj = kk >> 1; jj > 0; jj >>= 1) {
            for (int i = tid; i < 8192; i += 1024) {
                int ixj = i ^ jj;
                if (ixj > i) {
                    u64 x = sbuf[i], y = sbuf[ixj];
                    bool up = ((i & kk) == 0);
                    if ((x > y) == up) { sbuf[i] = y; sbuf[ixj] = x; }
                }
            }
            __syncthreads();
        }

    for (int s = tid; s < KSEL; s += 1024) {
        u64 ck = sbuf[s];
        int a = (int)(u32)ck;
        float score = probs[((size_t)b * A + a) * 2 + 1];
        float4 an = ((const float4*)anchors)[a];
        float4 dl = ((const float4*)deltas)[(size_t)b * A + a];
        float h = an.z - an.x, w = an.w - an.y;
        float cy = an.x + 0.5f * h + dl.x * 0.1f * h;
        float cx = an.y + 0.5f * w + dl.y * 0.1f * w;
        h *= expf(dl.z * 0.2f);
        w *= expf(dl.w * 0.2f);
        float y1 = cy - 0.5f * h, x1 = cx - 0.5f * w;
        float y2 = y1 + h,        x2 = x1 + w;
        y1 = fminf(fmaxf(y1, 0.f), 1024.f);
        x1 = fminf(fmaxf(x1, 0.f), 1024.f);
        y2 = fminf(fmaxf(y2, 0.f), 1024.f);
        x2 = fminf(fmaxf(x2, 0.f), 1024.f);
        ((float4*)boxes_sel)[(size_t)b * KSEL + s] = make_float4(y1, x1, y2, x2);
        scores_sel[(size_t)b * KSEL + s] = score;
    }
}

// ---------------- K5: suppression mask matrix (upper triangle only) ----------------
// mask[row i][word w] is only ever consumed for w >= chunk(i): within-chunk NMS uses
// the diagonal block; cross-chunk uses words of FUTURE chunks. Skip bj < bi.
__global__ __launch_bounds__(64)
void k_iou(const float* __restrict__ boxes_sel, u64* __restrict__ mask)
{
    __shared__ float4 rowb[64];
    int t = threadIdx.x;
    int bi = blockIdx.x, bj = blockIdx.y, b = blockIdx.z;
    if (bj < bi) return;                      // block-uniform early exit
    const float4* boxes = (const float4*)boxes_sel + (size_t)b * KSEL;
    int ri = bi * 64 + t;
    int j  = bj * 64 + t;
    rowb[t] = (ri < KSEL) ? boxes[ri] : make_float4(0.f, 0.f, 0.f, 0.f);
    float4 cb = (j < KSEL) ? boxes[j] : make_float4(0.f, 0.f, 0.f, 0.f);
    float areaC = (cb.z - cb.x) * (cb.w - cb.y);
    __syncthreads();
    u64 myword = 0;
    for (int r = 0; r < 64; ++r) {
        float4 rb = rowb[r];
        float areaR = (rb.z - rb.x) * (rb.w - rb.y);
        float iy1 = fmaxf(rb.x, cb.x), ix1 = fmaxf(rb.y, cb.y);
        float iy2 = fminf(rb.z, cb.z), ix2 = fminf(rb.w, cb.w);
        float inter = fmaxf(iy2 - iy1, 0.f) * fmaxf(ix2 - ix1, 0.f);
        float uni = fmaxf(areaR + areaC - inter, 1e-10f);
        bool sup = (j < KSEL) && (inter > 0.7f * uni);
        u64 word = __ballot(sup ? 1 : 0);
        if (r == t) myword = word;
    }
    if (ri < KSEL) mask[((size_t)b * KSEL + ri) * NW + bj] = myword;
}

// ---------------- K6: chunked greedy NMS with batched row-OR loads ----------------
// lane l holds removal words l (remv0) and 64+l (remv1). Per 64-box chunk:
// resolve intra-chunk greedy in scalar regs via the diagonal word, then OR kept
// boxes' full rows in 16-row batches: all 32 loads issued back-to-back
// (compile-time-indexed register arrays), ONE vmcnt wait per batch.
__global__ __launch_bounds__(64)
void k_nms(const u64* __restrict__ mask, int* __restrict__ keepidx, int* __restrict__ nkept)
{
    const int lane = threadIdx.x;
    const int b = blockIdx.x;
    const u64* mb = mask + (size_t)b * KSEL * NW;
    int* ki = keepidx + b * PC;

    u64 remv0 = 0, remv1 = 0;
    int kept = 0;
    u64 mcur = mb[(size_t)lane * NW];          // chunk 0 diagonal word

    for (int c = 0; c < NW; ++c) {
        // prefetch next chunk's diagonal word (latency hidden across this chunk)
        int rin = (c + 1) * 64 + lane;
        u64 mnext = (c + 1 < NW && rin < KSEL) ? mb[(size_t)rin * NW + (c + 1)] : 0ULL;

        u64 r = (c < 64) ? bcast64(remv0, c) : bcast64(remv1, c - 64);
        int rbn = KSEL - c * 64;
        u64 valid = (rbn >= 64) ? ~0ULL : ((1ULL << rbn) - 1ULL);
        u64 pend = valid & ~r;
        u64 keep = 0;
        while (pend) {                          // wave-uniform greedy resolve
            int bb = (int)(__ffsll((unsigned long long)pend) - 1);
            keep |= 1ULL << bb;
            u64 sup = bcast64(mcur, bb);
            pend &= ~(sup | (1ULL << bb));
        }
        int m = __popcll((unsigned long long)keep);
        // emit kept indices in rank order
        {
            u64 kk = keep; int q = 0;
            while (kk) {
                int bb = (int)(__ffsll((unsigned long long)kk) - 1); kk &= kk - 1;
                if (lane == 0 && kept + q < PC) ki[kept + q] = c * 64 + bb;
                ++q;
            }
        }
        kept += m;
        if (kept >= PC) { kept = PC; break; }

        // batched OR of kept rows into the distributed removal mask
        if (m) {
            int fb = (int)(__ffsll((unsigned long long)keep) - 1);  // safe addr for idle slots
            u64 kk = keep;
            while (kk) {
                int rix[16]; u64 vm[16];
#pragma unroll
                for (int q = 0; q < 16; ++q) {
                    bool v = (kk != 0);
                    int bb = v ? (int)(__ffsll((unsigned long long)kk) - 1) : fb;
                    if (v) kk &= kk - 1;
                    rix[q] = c * 64 + bb;
                    vm[q] = v ? ~0ULL : 0ULL;
                }
                u64 tv0[16], tv1[16];
#pragma unroll
                for (int q = 0; q < 16; ++q) {   // 32 independent loads, no waits between
                    const u64* row = mb + (size_t)rix[q] * NW;
                    tv0[q] = row[lane];
                    tv1[q] = (lane < NW - 64) ? row[64 + lane] : 0ULL;
                }
                u64 a0 = 0, a1 = 0;
#pragma unroll
                for (int q = 0; q < 16; ++q) { a0 |= tv0[q] & vm[q]; a1 |= tv1[q] & vm[q]; }
                remv0 |= a0; remv1 |= a1;
            }
        }
        mcur = mnext;
    }
    if (lane == 0) nkept[b] = kept;
}

// ---------------- K7: gather kept -> output ----------------
__global__ void k_out(const float* __restrict__ boxes_sel, const float* __restrict__ scores_sel,
                      const int* __restrict__ keepidx, const int* __restrict__ nkept,
                      float* __restrict__ out, int B)
{
    int idx = blockIdx.x * 256 + threadIdx.x;
    int nb = B * PC * 4;
    int ns = B * PC;
    if (idx < nb) {
        int b = idx / (PC * 4);
        int r = idx % (PC * 4);
        int s = r >> 2, c = r & 3;
        float v = 0.f;
        if (s < nkept[b]) {
            int i = keepidx[b * PC + s];
            v = boxes_sel[((size_t)b * KSEL + i) * 4 + c] * (1.0f / 1024.0f);
        }
        out[idx] = v;
    } else if (idx < nb + ns) {
        int r = idx - nb;
        int b = r / PC, s = r % PC;
        float v = 0.f;
        if (s < nkept[b]) v = scores_sel[(size_t)b * KSEL + keepidx[b * PC + s]];
        out[idx] = v;
    } else if (idx < nb + ns + B) {
        int b = idx - nb - ns;
        out[idx] = (float)nkept[b];
    }
}

extern "C" void kernel_launch(void* const* d_in, const int* in_sizes, int n_in,
                              void* d_out, int out_size, void* d_ws, size_t ws_size,
                              hipStream_t stream)
{
    const float* probs   = (const float*)d_in[0];
    const float* deltas  = (const float*)d_in[1];
    const float* anchors = (const float*)d_in[2];
    int A = in_sizes[2] / 4;
    int B = in_sizes[0] / (2 * A);

    char* w = (char*)d_ws;
    size_t off = 0;
    // zero region (single memset): hist16 | hist2 | cnt
    u32* hist16 = (u32*)(w + off);     off += (size_t)B * HB * sizeof(u32);
    u32* hist2  = (u32*)(w + off);     off += (size_t)B * HB * sizeof(u32);
    u32* cnt    = (u32*)(w + off);     off += (size_t)B * sizeof(u32);
    size_t zero_bytes = off;
    off = (off + 15) & ~(size_t)15;
    u32* keys = (u32*)(w + off);       off += (size_t)B * A * sizeof(u32);
    u32* pfx  = (u32*)(w + off);       off += (size_t)B * sizeof(u32);
    u32* remq = (u32*)(w + off);       off += (size_t)B * sizeof(u32);
    u32* T    = (u32*)(w + off);       off += (size_t)B * sizeof(u32);
    off = (off + 15) & ~(size_t)15;
    u64* cand = (u64*)(w + off);       off += (size_t)B * CAP * sizeof(u64);
    float* boxes_sel  = (float*)(w + off); off += (size_t)B * KSEL * 4 * sizeof(float);
    float* scores_sel = (float*)(w + off); off += (size_t)B * KSEL * sizeof(float);
    int* keepidx = (int*)(w + off);        off += (size_t)B * PC * sizeof(int);
    int* nkept   = (int*)(w + off);        off += (size_t)B * sizeof(int);
    off = (off + 15) & ~(size_t)15;
    u64* mask = (u64*)(w + off);           off += (size_t)B * KSEL * NW * sizeof(u64);

    hipMemsetAsync(hist16, 0, zero_bytes, stream);

    dim3 gA((A + 255) / 256, B);
    k_keys_hist<<<gA, 256, 0, stream>>>(probs, keys, hist16, A);
    k_pick<0><<<B, 1024, 0, stream>>>(hist16, nullptr, nullptr, pfx, remq, nullptr);
    k_hist2<<<gA, 256, 0, stream>>>(keys, pfx, hist2, A);
    k_pick<1><<<B, 1024, 0, stream>>>(hist2, remq, pfx, nullptr, nullptr, T);
    k_collect<<<gA, 256, 0, stream>>>(keys, T, cnt, cand, A);
    k_sortdecode<<<B, 1024, 0, stream>>>(probs, deltas, anchors, cand, cnt,
                                         boxes_sel, scores_sel, A);
    k_iou<<<dim3(NW, NW, B), 64, 0, stream>>>(boxes_sel, mask);
    k_nms<<<B, 64, 0, stream>>>(mask, keepidx, nkept);
    int outn = B * (PC * 4 + PC + 1);
    k_out<<<(outn + 255) / 256, 256, 0, stream>>>(boxes_sel, scores_sel, keepidx, nkept,
                                                  (float*)d_out, B);
}

// Round 5
// 595.869 us; speedup vs baseline: 1.9233x; 1.3768x over previous
//
#include <hip/hip_runtime.h>
#include <stdint.h>

typedef unsigned int u32;
typedef unsigned long long u64;

#define KSEL 6000      // pre_nms_limit
#define PC   1000      // proposal_count
#define NW   94        // ceil(KSEL/64) removal-mask words
#define CAP  8000      // candidate collection cap
#define HB   65536     // low-16-bit histogram bins

// broadcast lane `src` (wave-uniform) of a per-lane u64 to all lanes, result in SGPRs
__device__ inline u64 bcast64(u64 v, int src) {
    int s = __builtin_amdgcn_readfirstlane(src);
    u32 lo = __builtin_amdgcn_readlane((u32)(v & 0xFFFFFFFFULL), s);
    u32 hi = __builtin_amdgcn_readlane((u32)(v >> 32), s);
    return ((u64)hi << 32) | lo;
}

// ---------------- K0: keys + top-8-bit histogram (LDS-privatized) ----------------
// 4 sub-histograms (one per wave) cut LDS same-address atomic serialization;
// one global flush of 256 atomics/block -> per-bin global contention = #blocks.
#define CH 2048        // elements per block
__global__ __launch_bounds__(256)
void k_keys_hist8(const float* __restrict__ probs, u32* __restrict__ keys,
                  u32* __restrict__ hist8, int A)
{
    __shared__ u32 lh[4][256];
    const int tid = threadIdx.x, b = blockIdx.y;
    const int w = tid >> 6;
    for (int q = tid; q < 1024; q += 256) ((u32*)lh)[q] = 0;
    __syncthreads();
    int base = blockIdx.x * CH;
#pragma unroll
    for (int it = 0; it < CH / 256; ++it) {
        int a = base + it * 256 + tid;
        if (a < A) {
            size_t i = (size_t)b * A + a;
            u32 u = __float_as_uint(probs[i * 2 + 1]);
            u = (u & 0x80000000u) ? ~u : (u | 0x80000000u);   // float order -> uint order
            keys[i] = u;
            atomicAdd(&lh[w][u >> 24], 1u);
        }
    }
    __syncthreads();
    u32 s = lh[0][tid] + lh[1][tid] + lh[2][tid] + lh[3][tid];
    if (s) atomicAdd(&hist8[b * 256 + tid], s);
}

// ---------------- K1: pick bin from a 256-bin histogram (suffix-sum) ----------------
// LEVEL 0: -> pfx8, rem.  LEVEL 1: -> pfx16 = (pfx8<<8)|bin, rem.
template <int LEVEL>
__global__ __launch_bounds__(256)
void k_pick8(const u32* __restrict__ hist, const u32* __restrict__ rem_in,
             const u32* __restrict__ pfx_in, u32* __restrict__ pfx_out,
             u32* __restrict__ rem_out)
{
    __shared__ u32 s[256];
    const int t = threadIdx.x, b = blockIdx.x;
    s[t] = hist[b * 256 + t];
    __syncthreads();
    for (int off = 1; off < 256; off <<= 1) {       // suffix (descending) inclusive scan
        u32 add = (t + off < 256) ? s[t + off] : 0u;
        __syncthreads();
        s[t] += add;
        __syncthreads();
    }
    u32 rem = (LEVEL == 0) ? (u32)KSEL : rem_in[b];
    u32 suf = s[t];
    u32 sufn = (t < 255) ? s[t + 1] : 0u;
    if (suf >= rem && sufn < rem) {                 // unique crossing bin
        if (LEVEL == 0) pfx_out[b] = (u32)t;
        else            pfx_out[b] = (pfx_in[b] << 8) | (u32)t;
        rem_out[b] = rem - sufn;
    }
}

// ---------------- K2: second-8-bit histogram conditioned on pfx8 (LDS) ----------------
__global__ __launch_bounds__(256)
void k_hist8b(const u32* __restrict__ keys, const u32* __restrict__ pfx8,
              u32* __restrict__ hist8b, int A)
{
    __shared__ u32 lh[4][256];
    const int tid = threadIdx.x, b = blockIdx.y;
    const int w = tid >> 6;
    for (int q = tid; q < 1024; q += 256) ((u32*)lh)[q] = 0;
    __syncthreads();
    const u32 p = pfx8[b];
    int base = blockIdx.x * CH;
#pragma unroll
    for (int it = 0; it < CH / 256; ++it) {
        int a = base + it * 256 + tid;
        if (a < A) {
            u32 k = keys[(size_t)b * A + a];
            if ((k >> 24) == p) atomicAdd(&lh[w][(k >> 16) & 0xFFu], 1u);
        }
    }
    __syncthreads();
    u32 s = lh[0][tid] + lh[1][tid] + lh[2][tid] + lh[3][tid];
    if (s) atomicAdd(&hist8b[b * 256 + tid], s);
}

// ---------------- K3: low-16-bit histogram conditioned on pfx16 (global, sparse) ----------------
__global__ void k_hist16(const u32* __restrict__ keys, const u32* __restrict__ pfx16,
                         u32* __restrict__ hist16g, int A)
{
    int a = blockIdx.x * 256 + threadIdx.x;
    int b = blockIdx.y;
    if (a >= A) return;
    u32 k = keys[(size_t)b * A + a];
    if ((k >> 16) == pfx16[b])
        atomicAdd(&hist16g[(size_t)b * HB + (k & 0xFFFFu)], 1u);   // few-thousand hits over 64k bins
}

// ---------------- K4: final pick over 65536 bins -> exact 32-bit T ----------------
__global__ __launch_bounds__(1024)
void k_pick16(const u32* __restrict__ hist, const u32* __restrict__ rem_in,
              const u32* __restrict__ pfx_in, u32* __restrict__ T_out)
{
    __shared__ u32 part[1024];
    const int t = threadIdx.x, b = blockIdx.x;
    const u32* h = hist + (size_t)b * HB;
    const int hi = HB - 1 - t * 64;            // my 64-bin chunk, descending
    u32 s = 0;
#pragma unroll 8
    for (int q = 0; q < 64; ++q) s += h[hi - q];
    part[t] = s;
    __syncthreads();
    u32 run = s;
    for (int off = 1; off < 1024; off <<= 1) {
        u32 add = (t >= off) ? part[t - off] : 0u;
        __syncthreads();
        run += add;
        part[t] = run;
        __syncthreads();
    }
    const u32 rem = rem_in[b];
    u32 excl = run - s;
    if (excl < rem && rem <= run) {            // threshold bin is in my chunk
        u32 cum = excl;
        for (int q = 0; q < 64; ++q) {
            u32 c = h[hi - q];
            if (cum + c >= rem) { T_out[b] = (pfx_in[b] << 16) | (u32)(hi - q); break; }
            cum += c;
        }
    }
}

// ---------------- K5: collect (~key, index) for all keys >= T ----------------
__global__ void k_collect(const u32* __restrict__ keys, const u32* __restrict__ T,
                          u32* __restrict__ cnt, u64* __restrict__ cand, int A)
{
    int a = blockIdx.x * 256 + threadIdx.x;
    int b = blockIdx.y;
    if (a >= A) return;
    u32 k = keys[(size_t)b * A + a];
    if (k >= T[b]) {
        u32 pos = atomicAdd(&cnt[b], 1u);
        if (pos < CAP) cand[(size_t)b * CAP + pos] = ((u64)(~k) << 32) | (u32)a;
    }
}

// ---------------- K6: per-sample stable sort + box decode ----------------
__global__ __launch_bounds__(1024)
void k_sortdecode(const float* __restrict__ probs, const float* __restrict__ deltas,
                  const float* __restrict__ anchors, const u64* __restrict__ cand,
                  const u32* __restrict__ cntg, float* __restrict__ boxes_sel,
                  float* __restrict__ scores_sel, int A)
{
    __shared__ u64 sbuf[8192];                 // 64 KiB
    const int tid = threadIdx.x, b = blockIdx.x;
    int cnt = (int)cntg[b]; if (cnt > CAP) cnt = CAP;
    for (int i = tid; i < cnt; i += 1024) sbuf[i] = cand[(size_t)b * CAP + i];
    for (int i = cnt + tid; i < 8192; i += 1024) sbuf[i] = ~0ULL;
    __syncthreads();

    for (int kk = 2; kk <= 8192; kk <<= 1)
        for (int jj = kk >> 1; jj > 0; jj >>= 1) {
            for (int i = tid; i < 8192; i += 1024) {
                int ixj = i ^ jj;
                if (ixj > i) {
                    u64 x = sbuf[i], y = sbuf[ixj];
                    bool up = ((i & kk) == 0);
                    if ((x > y) == up) { sbuf[i] = y; sbuf[ixj] = x; }
                }
            }
            __syncthreads();
        }

    for (int s = tid; s < KSEL; s += 1024) {
        u64 ck = sbuf[s];
        int a = (int)(u32)ck;
        float score = probs[((size_t)b * A + a) * 2 + 1];
        float4 an = ((const float4*)anchors)[a];
        float4 dl = ((const float4*)deltas)[(size_t)b * A + a];
        float h = an.z - an.x, w = an.w - an.y;
        float cy = an.x + 0.5f * h + dl.x * 0.1f * h;
        float cx = an.y + 0.5f * w + dl.y * 0.1f * w;
        h *= expf(dl.z * 0.2f);
        w *= expf(dl.w * 0.2f);
        float y1 = cy - 0.5f * h, x1 = cx - 0.5f * w;
        float y2 = y1 + h,        x2 = x1 + w;
        y1 = fminf(fmaxf(y1, 0.f), 1024.f);
        x1 = fminf(fmaxf(x1, 0.f), 1024.f);
        y2 = fminf(fmaxf(y2, 0.f), 1024.f);
        x2 = fminf(fmaxf(x2, 0.f), 1024.f);
        ((float4*)boxes_sel)[(size_t)b * KSEL + s] = make_float4(y1, x1, y2, x2);
        scores_sel[(size_t)b * KSEL + s] = score;
    }
}

// ---------------- K7: suppression mask matrix (upper triangle only) ----------------
__global__ __launch_bounds__(64)
void k_iou(const float* __restrict__ boxes_sel, u64* __restrict__ mask)
{
    __shared__ float4 rowb[64];
    int t = threadIdx.x;
    int bi = blockIdx.x, bj = blockIdx.y, b = blockIdx.z;
    if (bj < bi) return;                      // block-uniform early exit
    const float4* boxes = (const float4*)boxes_sel + (size_t)b * KSEL;
    int ri = bi * 64 + t;
    int j  = bj * 64 + t;
    rowb[t] = (ri < KSEL) ? boxes[ri] : make_float4(0.f, 0.f, 0.f, 0.f);
    float4 cb = (j < KSEL) ? boxes[j] : make_float4(0.f, 0.f, 0.f, 0.f);
    float areaC = (cb.z - cb.x) * (cb.w - cb.y);
    __syncthreads();
    u64 myword = 0;
    for (int r = 0; r < 64; ++r) {
        float4 rb = rowb[r];
        float areaR = (rb.z - rb.x) * (rb.w - rb.y);
        float iy1 = fmaxf(rb.x, cb.x), ix1 = fmaxf(rb.y, cb.y);
        float iy2 = fminf(rb.z, cb.z), ix2 = fminf(rb.w, cb.w);
        float inter = fmaxf(iy2 - iy1, 0.f) * fmaxf(ix2 - ix1, 0.f);
        float uni = fmaxf(areaR + areaC - inter, 1e-10f);
        bool sup = (j < KSEL) && (inter > 0.7f * uni);
        u64 word = __ballot(sup ? 1 : 0);
        if (r == t) myword = word;
    }
    if (ri < KSEL) mask[((size_t)b * KSEL + ri) * NW + bj] = myword;
}

// ---------------- K8: chunked greedy NMS with batched row-OR loads ----------------
__global__ __launch_bounds__(64)
void k_nms(const u64* __restrict__ mask, int* __restrict__ keepidx, int* __restrict__ nkept)
{
    const int lane = threadIdx.x;
    const int b = blockIdx.x;
    const u64* mb = mask + (size_t)b * KSEL * NW;
    int* ki = keepidx + b * PC;

    u64 remv0 = 0, remv1 = 0;
    int kept = 0;
    u64 mcur = mb[(size_t)lane * NW];          // chunk 0 diagonal word

    for (int c = 0; c < NW; ++c) {
        int rin = (c + 1) * 64 + lane;
        u64 mnext = (c + 1 < NW && rin < KSEL) ? mb[(size_t)rin * NW + (c + 1)] : 0ULL;

        u64 r = (c < 64) ? bcast64(remv0, c) : bcast64(remv1, c - 64);
        int rbn = KSEL - c * 64;
        u64 valid = (rbn >= 64) ? ~0ULL : ((1ULL << rbn) - 1ULL);
        u64 pend = valid & ~r;
        u64 keep = 0;
        while (pend) {                          // wave-uniform greedy resolve
            int bb = (int)(__ffsll((unsigned long long)pend) - 1);
            keep |= 1ULL << bb;
            u64 sup = bcast64(mcur, bb);
            pend &= ~(sup | (1ULL << bb));
        }
        int m = __popcll((unsigned long long)keep);
        {
            u64 kk = keep; int q = 0;
            while (kk) {
                int bb = (int)(__ffsll((unsigned long long)kk) - 1); kk &= kk - 1;
                if (lane == 0 && kept + q < PC) ki[kept + q] = c * 64 + bb;
                ++q;
            }
        }
        kept += m;
        if (kept >= PC) { kept = PC; break; }

        if (m) {
            int fb = (int)(__ffsll((unsigned long long)keep) - 1);
            u64 kk = keep;
            while (kk) {
                int rix[16]; u64 vm[16];
#pragma unroll
                for (int q = 0; q < 16; ++q) {
                    bool v = (kk != 0);
                    int bb = v ? (int)(__ffsll((unsigned long long)kk) - 1) : fb;
                    if (v) kk &= kk - 1;
                    rix[q] = c * 64 + bb;
                    vm[q] = v ? ~0ULL : 0ULL;
                }
                u64 tv0[16], tv1[16];
#pragma unroll
                for (int q = 0; q < 16; ++q) {   // 32 independent loads, one wait
                    const u64* row = mb + (size_t)rix[q] * NW;
                    tv0[q] = row[lane];
                    tv1[q] = (lane < NW - 64) ? row[64 + lane] : 0ULL;
                }
                u64 a0 = 0, a1 = 0;
#pragma unroll
                for (int q = 0; q < 16; ++q) { a0 |= tv0[q] & vm[q]; a1 |= tv1[q] & vm[q]; }
                remv0 |= a0; remv1 |= a1;
            }
        }
        mcur = mnext;
    }
    if (lane == 0) nkept[b] = kept;
}

// ---------------- K9: gather kept -> output ----------------
__global__ void k_out(const float* __restrict__ boxes_sel, const float* __restrict__ scores_sel,
                      const int* __restrict__ keepidx, const int* __restrict__ nkept,
                      float* __restrict__ out, int B)
{
    int idx = blockIdx.x * 256 + threadIdx.x;
    int nb = B * PC * 4;
    int ns = B * PC;
    if (idx < nb) {
        int b = idx / (PC * 4);
        int r = idx % (PC * 4);
        int s = r >> 2, c = r & 3;
        float v = 0.f;
        if (s < nkept[b]) {
            int i = keepidx[b * PC + s];
            v = boxes_sel[((size_t)b * KSEL + i) * 4 + c] * (1.0f / 1024.0f);
        }
        out[idx] = v;
    } else if (idx < nb + ns) {
        int r = idx - nb;
        int b = r / PC, s = r % PC;
        float v = 0.f;
        if (s < nkept[b]) v = scores_sel[(size_t)b * KSEL + keepidx[b * PC + s]];
        out[idx] = v;
    } else if (idx < nb + ns + B) {
        int b = idx - nb - ns;
        out[idx] = (float)nkept[b];
    }
}

extern "C" void kernel_launch(void* const* d_in, const int* in_sizes, int n_in,
                              void* d_out, int out_size, void* d_ws, size_t ws_size,
                              hipStream_t stream)
{
    const float* probs   = (const float*)d_in[0];
    const float* deltas  = (const float*)d_in[1];
    const float* anchors = (const float*)d_in[2];
    int A = in_sizes[2] / 4;
    int B = in_sizes[0] / (2 * A);

    char* w = (char*)d_ws;
    size_t off = 0;
    // zero region (single memset): hist8a | hist8b | hist16g | cnt
    u32* hist8a  = (u32*)(w + off);    off += (size_t)B * 256 * sizeof(u32);
    u32* hist8b  = (u32*)(w + off);    off += (size_t)B * 256 * sizeof(u32);
    u32* hist16g = (u32*)(w + off);    off += (size_t)B * HB * sizeof(u32);
    u32* cnt     = (u32*)(w + off);    off += (size_t)B * sizeof(u32);
    size_t zero_bytes = off;
    off = (off + 15) & ~(size_t)15;
    u32* keys = (u32*)(w + off);       off += (size_t)B * A * sizeof(u32);
    u32* pfxA = (u32*)(w + off);       off += (size_t)B * sizeof(u32);
    u32* remA = (u32*)(w + off);       off += (size_t)B * sizeof(u32);
    u32* pfxB = (u32*)(w + off);       off += (size_t)B * sizeof(u32);
    u32* remB = (u32*)(w + off);       off += (size_t)B * sizeof(u32);
    u32* T    = (u32*)(w + off);       off += (size_t)B * sizeof(u32);
    off = (off + 15) & ~(size_t)15;
    u64* cand = (u64*)(w + off);       off += (size_t)B * CAP * sizeof(u64);
    float* boxes_sel  = (float*)(w + off); off += (size_t)B * KSEL * 4 * sizeof(float);
    float* scores_sel = (float*)(w + off); off += (size_t)B * KSEL * sizeof(float);
    int* keepidx = (int*)(w + off);        off += (size_t)B * PC * sizeof(int);
    int* nkept   = (int*)(w + off);        off += (size_t)B * sizeof(int);
    off = (off + 15) & ~(size_t)15;
    u64* mask = (u64*)(w + off);           off += (size_t)B * KSEL * NW * sizeof(u64);

    hipMemsetAsync(hist8a, 0, zero_bytes, stream);

    dim3 gCH((A + CH - 1) / CH, B);
    dim3 gA((A + 255) / 256, B);
    k_keys_hist8<<<gCH, 256, 0, stream>>>(probs, keys, hist8a, A);
    k_pick8<0><<<B, 256, 0, stream>>>(hist8a, nullptr, nullptr, pfxA, remA);
    k_hist8b<<<gCH, 256, 0, stream>>>(keys, pfxA, hist8b, A);
    k_pick8<1><<<B, 256, 0, stream>>>(hist8b, remA, pfxA, pfxB, remB);
    k_hist16<<<gA, 256, 0, stream>>>(keys, pfxB, hist16g, A);
    k_pick16<<<B, 1024, 0, stream>>>(hist16g, remB, pfxB, T);
    k_collect<<<gA, 256, 0, stream>>>(keys, T, cnt, cand, A);
    k_sortdecode<<<B, 1024, 0, stream>>>(probs, deltas, anchors, cand, cnt,
                                         boxes_sel, scores_sel, A);
    k_iou<<<dim3(NW, NW, B), 64, 0, stream>>>(boxes_sel, mask);
    k_nms<<<B, 64, 0, stream>>>(mask, keepidx, nkept);
    int outn = B * (PC * 4 + PC + 1);
    k_out<<<(outn + 255) / 256, 256, 0, stream>>>(boxes_sel, scores_sel, keepidx, nkept,
                                                  (float*)d_out, B);
}